// Round 11
// baseline (146.041 us; speedup 1.0000x reference)
//
#include <hip/hip_runtime.h>
#include <hip/hip_bf16.h>
#include <math.h>

// Shapes (fixed by the reference)
#define B_SZ   256
#define L_SZ   512
#define FD_SZ  64
#define H1_SZ  512
#define H2_SZ  512
#define G_SZ   32
#define DH_SZ  256
#define M_SZ   (B_SZ * L_SZ)   // 131072 rows

typedef __bf16 bfx8 __attribute__((ext_vector_type(8)));
typedef __bf16 bfx4 __attribute__((ext_vector_type(4)));
typedef float  f32x4 __attribute__((ext_vector_type(4)));
typedef float  f32x16 __attribute__((ext_vector_type(16)));

__device__ __forceinline__ float gelu_exact(float x) {
  return 0.5f * x * (1.0f + erff(x * 0.70710678118654752440f));
}
// tanh-form gelu via sigmoid; log2(e) folded in so v_exp_f32 is used directly.
__device__ __forceinline__ float gelu_fast(float x) {
  float x2 = x * x;
  float w = x * fmaf(0.102943398f, x2, 2.30220931f);
  float e = __builtin_amdgcn_exp2f(-w);
  return x * __builtin_amdgcn_rcpf(1.0f + e);
}
__device__ __forceinline__ float softplus_f(float x) {
  return (x > 20.0f) ? x : log1pf(expf(x));
}
__device__ __forceinline__ __bf16 f2bf(float f) { return (__bf16)f; }

#define MFMA16(a, b, c) __builtin_amdgcn_mfma_f32_16x16x32_bf16((a), (b), (c), 0, 0, 0)
#define MFMA32(a, b, c) __builtin_amdgcn_mfma_f32_32x32x16_bf16((a), (b), (c), 0, 0, 0)

// ---------------------------------------------------------------------------
// Repack (all fp32 -> bf16 MFMA fragment order):
//  W1 (64x512) -> 16x16x32 A/B-frag: block mb*2+ks; lane l holds
//    W1[ks*32+(l>>4)*8+j][16*mb+(l&15)].
//  W2 (512x512) -> 32x32x16 B-frag: block nb*32+ks; lane l holds
//    W2[16*ks+(l>>5)*8+j][32*nb+(l&31)].
//  W3 = [wa|wt|0...] (512x16) -> 16x16x32 B-frag: block ks; lane l holds
//    W3[32*ks+(l>>4)*8+j][l&15]  (col0=wa, col1=wt, cols 2..15 = 0).
// Also zeroes `pooled` (512 KB).
// ---------------------------------------------------------------------------
__global__ void repack_kernel(const float* __restrict__ W1,
                              const float* __restrict__ W2,
                              const float* __restrict__ wa,
                              const float* __restrict__ wt,
                              __bf16* __restrict__ W1p,
                              __bf16* __restrict__ W2p,
                              __bf16* __restrict__ W3p,
                              float* __restrict__ pooled) {
  int t = blockIdx.x * 256 + threadIdx.x;
  // zero pooled: 131072 floats = 32768 float4
  if (t < 32768)
    *reinterpret_cast<float4*>(pooled + (size_t)t * 4) = (float4){0.f, 0.f, 0.f, 0.f};
  if (t < 4096) {  // W1: 64 blocks * 64 lanes
    int lane = t & 63, blk = t >> 6;
    int ks = blk & 1, mb = blk >> 1;
    int col = 16 * mb + (lane & 15);
    int kbase = ks * 32 + (lane >> 4) * 8;
    bfx8 o;
#pragma unroll
    for (int j = 0; j < 8; ++j) o[j] = f2bf(W1[(size_t)(kbase + j) * H1_SZ + col]);
    *reinterpret_cast<bfx8*>(W1p + (size_t)t * 8) = o;
  } else if (t < 4096 + 32768) {  // W2: 512 blocks * 64 lanes (32x32x16 frags)
    int t2 = t - 4096;
    int lane = t2 & 63, blk = t2 >> 6;
    int ks = blk & 31, nb = blk >> 5;
    int col = 32 * nb + (lane & 31);
    int kbase = 16 * ks + (lane >> 5) * 8;
    bfx8 o;
#pragma unroll
    for (int j = 0; j < 8; ++j) o[j] = f2bf(W2[(size_t)(kbase + j) * H2_SZ + col]);
    *reinterpret_cast<bfx8*>(W2p + (size_t)t2 * 8) = o;
  } else if (t < 4096 + 32768 + 1024) {  // W3: 16 blocks * 64 lanes
    int t3 = t - (4096 + 32768);
    int lane = t3 & 63, ks = t3 >> 6;
    int col = lane & 15;
    int kbase = 32 * ks + (lane >> 4) * 8;
    bfx8 o;
#pragma unroll
    for (int j = 0; j < 8; ++j)
      o[j] = (col == 0) ? f2bf(wa[kbase + j])
           : (col == 1) ? f2bf(wt[kbase + j]) : (__bf16)0.0f;
    *reinterpret_cast<bfx8*>(W3p + (size_t)t3 * 8) = o;
  }
}

// ---------------------------------------------------------------------------
// Fused kernel: 64 rows per workgroup, 1024 threads (16 waves), 8 waves/SIMD.
//  Stage X tile -> bf16 LDS; GEMM1 (16x16x32, transposed) -> gelu -> H1s;
//  GEMM2 (32x32x16, K=512, W2 from L2) -> V=gelu(h2+b2) -> bf16 Vs (reuses
//  H1s); absorb/atten via MFMA reduce GEMM (V @ [wa|wt], waves 0..3);
//  pooled accumulated in fp32 + global atomics.
// LDS: 8K Xs + 64K H1s = 72 KB -> 2 blocks/CU -> 32 waves/CU (HW max).
// ---------------------------------------------------------------------------
__global__ __launch_bounds__(1024, 8) void fused_kernel(
    const float* __restrict__ Xl,
    const __bf16* __restrict__ W1p, const __bf16* __restrict__ W2p,
    const __bf16* __restrict__ W3p,
    const float* __restrict__ b1, const float* __restrict__ b2,
    const float* __restrict__ ba, const float* __restrict__ bt,
    float* __restrict__ absorbW, float* __restrict__ attenW,
    float* __restrict__ pooled) {
  __shared__ __bf16 Xs[64 * 64];      // 8 KB, [row][k], 16B-chunk XOR swizzle
  __shared__ __bf16 H1s[64 * 512];    // 64 KB; reused as Vs after GEMM2

  const int tid = threadIdx.x;
  const int lane = tid & 63;
  const int w = tid >> 6;        // wave 0..15
  const int g = lane >> 4;       // k-group 0..3 (16x16x32 frags)
  const int c = lane & 15;       // row/col within 16x16 fragment
  const int c32 = lane & 31;     // col within 32x32 fragment
  const int kg = lane >> 5;      // k-group 0..1 (32x32x16 frags)
  const int R0 = blockIdx.x * 64;
  const int bidx = R0 >> 9;      // batch index (tiles aligned within batch)

  // ---- stage Xl tile (64x64 fp32 -> bf16 LDS, swizzled; convert ONCE) ----
  {
    int idx = tid;                // float4 unit 0..1023 (one per thread)
    int r = idx >> 4;
    int c4 = idx & 15;            // 16 float4 per row
    float4 v = *reinterpret_cast<const float4*>(Xl + (size_t)(R0 + r) * FD_SZ + c4 * 4);
    bfx4 bv;
    bv[0] = f2bf(v.x); bv[1] = f2bf(v.y); bv[2] = f2bf(v.z); bv[3] = f2bf(v.w);
    int chunk = c4 >> 1;          // 8-elem (16B) chunk 0..7
    int off = r * 64 + (((chunk ^ (r & 7)) << 3) + (c4 & 1) * 4);
    *reinterpret_cast<bfx4*>(&Xs[off]) = bv;
  }
  __syncthreads();

  // ---- GEMM1 (transposed): wave computes h1 cols 32w..32w+31 --------------
  f32x4 acc1[2][4];
#pragma unroll
  for (int mi = 0; mi < 2; ++mi)
#pragma unroll
    for (int ni = 0; ni < 4; ++ni) acc1[mi][ni] = (f32x4){0.f, 0.f, 0.f, 0.f};

#pragma unroll
  for (int ks = 0; ks < 2; ++ks) {
    bfx8 a1[2];
#pragma unroll
    for (int mi = 0; mi < 2; ++mi) {
      int mb = 2 * w + mi;
      a1[mi] = *reinterpret_cast<const bfx8*>(W1p + ((size_t)(mb * 2 + ks) * 64 + lane) * 8);
    }
    bfx8 bx[4];
#pragma unroll
    for (int ni = 0; ni < 4; ++ni) {
      int r = 16 * ni + c;
      int chunk = ks * 4 + g;
      bx[ni] = *reinterpret_cast<const bfx8*>(&Xs[r * 64 + ((chunk ^ (r & 7)) << 3)]);
    }
#pragma unroll
    for (int mi = 0; mi < 2; ++mi)
#pragma unroll
      for (int ni = 0; ni < 4; ++ni)
        acc1[mi][ni] = MFMA16(a1[mi], bx[ni], acc1[mi][ni]);
  }

  // epilogue GEMM1: bias + gelu -> bf16 -> H1s[row][k] (k = 16*mb + 4*g + reg)
#pragma unroll
  for (int mi = 0; mi < 2; ++mi) {
    int mb = 2 * w + mi;
    float4 bias4 = *reinterpret_cast<const float4*>(b1 + 16 * mb + 4 * g);
#pragma unroll
    for (int ni = 0; ni < 4; ++ni) {
      int r = 16 * ni + c;                 // x-row (0..63)
      bfx4 pv;
      pv[0] = f2bf(gelu_fast(acc1[mi][ni][0] + bias4.x));
      pv[1] = f2bf(gelu_fast(acc1[mi][ni][1] + bias4.y));
      pv[2] = f2bf(gelu_fast(acc1[mi][ni][2] + bias4.z));
      pv[3] = f2bf(gelu_fast(acc1[mi][ni][3] + bias4.w));
      int kchunk = 2 * mb + (g >> 1);      // (16*mb + 4*g)/8
      int off = r * 512 + ((kchunk ^ (r & 31)) << 3) + (g & 1) * 4;
      *reinterpret_cast<bfx4*>(&H1s[off]) = pv;
    }
  }
  __syncthreads();

  // ---- GEMM2 (32x32x16): wave w owns cols 32w..32w+31 (nb=w), rows 0..63 --
  f32x16 acc2[2];   // [mblk] -> 32 AGPR
#pragma unroll
  for (int m = 0; m < 2; ++m)
#pragma unroll
    for (int q = 0; q < 16; ++q) acc2[m][q] = 0.0f;

  const __bf16* wpb = W2p + ((size_t)w * 32 * 64 + lane) * 8;
  for (int ks = 0; ks < 32; ++ks) {
    bfx8 a2[2];
#pragma unroll
    for (int m = 0; m < 2; ++m) {
      int r = 32 * m + c32;
      int chunk = 2 * ks + kg;
      a2[m] = *reinterpret_cast<const bfx8*>(&H1s[r * 512 + ((chunk ^ (r & 31)) << 3)]);
    }
    bfx8 bw = *reinterpret_cast<const bfx8*>(wpb + (size_t)ks * 512);
    __builtin_amdgcn_s_setprio(1);
    acc2[0] = MFMA32(a2[0], bw, acc2[0]);
    acc2[1] = MFMA32(a2[1], bw, acc2[1]);
    __builtin_amdgcn_s_setprio(0);
  }
  __syncthreads();   // all waves done READING H1s; safe to overwrite as Vs

  // ---- epilogue GEMM2: V = gelu(h2 + b2) -> bf16 Vs (reuse H1s) + pooled ---
  // acc2 C layout (32x32): col=lane&31, row=(reg&3)+8*(reg>>2)+4*(lane>>5)
  __bf16* Vs = H1s;
  const int colg = 32 * w + c32;
  const float b2v = b2[colg];
  const int cchunk = colg >> 3;
  const int clow = colg & 7;
  float pool0 = 0.0f;
#pragma unroll
  for (int m = 0; m < 2; ++m) {
#pragma unroll
    for (int reg = 0; reg < 16; ++reg) {
      float v = gelu_fast(acc2[m][reg] + b2v);
      pool0 += v;
      int row = 32 * m + (reg & 3) + 8 * (reg >> 2) + 4 * kg;
      Vs[row * 512 + ((cchunk ^ (row & 31)) << 3) + clow] = f2bf(v);
    }
  }
  // pooled: combine kg halves (rows 0..31 vs 32.. within sets), one atomic/col
  pool0 += __shfl_xor(pool0, 32, 64);
  if (lane < 32)
    atomicAdd(&pooled[bidx * H2_SZ + colg], pool0);
  __syncthreads();

  // ---- absorb/atten via MFMA reduce: [V (64x512)] @ [wa|wt (512x16)] ------
  // A-frag: lane holds V[16w + (lane&15)][32ks + 8g + j]; B-frag = W3p.
  // C: col=lane&15 (0=absorb,1=atten), row=(lane>>4)*4+reg = L-row 16w+4g+reg
  if (w < 4) {
    f32x4 racc = (f32x4){0.f, 0.f, 0.f, 0.f};
    int r = 16 * w + c;
    for (int ks = 0; ks < 16; ++ks) {
      int chunk = 4 * ks + g;
      bfx8 av = *reinterpret_cast<const bfx8*>(&Vs[r * 512 + ((chunk ^ (r & 31)) << 3)]);
      bfx8 bw3 = *reinterpret_cast<const bfx8*>(W3p + ((size_t)ks * 64 + lane) * 8);
      racc = MFMA16(av, bw3, racc);
    }
    if (c == 0) {
#pragma unroll
      for (int reg = 0; reg < 4; ++reg)
        absorbW[R0 + 16 * w + 4 * g + reg] = softplus_f(racc[reg] + ba[0]);
    } else if (c == 1) {
#pragma unroll
      for (int reg = 0; reg < 4; ++reg)
        attenW[R0 + 16 * w + 4 * g + reg] = softplus_f(racc[reg] + bt[0]);
    }
  }
}

// ---------------------------------------------------------------------------
// Finalize: per-b reversed exclusive-cumsum scan + captured, pooled head, out
// ---------------------------------------------------------------------------
__global__ __launch_bounds__(256) void finalize_kernel(
    const float* __restrict__ Xg,
    const float* __restrict__ absorbW, const float* __restrict__ attenW,
    const float* __restrict__ pooled,
    const float* __restrict__ Wd1, const float* __restrict__ bd1,
    const float* __restrict__ Wd2, const float* __restrict__ bd2,
    float* __restrict__ out) {
  __shared__ float s0[512];
  __shared__ float s1[512];
  __shared__ float sab[512];
  __shared__ float zz[544];
  __shared__ float redc[4];
  __shared__ float redd[4];

  const int b = blockIdx.x;
  const int t = threadIdx.x;
  const int i0 = t, i1 = t + 256;

  // load time-reversed absorb/atten
  float a0 = attenW[b * L_SZ + (L_SZ - 1 - i0)];
  float a1 = attenW[b * L_SZ + (L_SZ - 1 - i1)];
  sab[i0] = absorbW[b * L_SZ + (L_SZ - 1 - i0)];
  sab[i1] = absorbW[b * L_SZ + (L_SZ - 1 - i1)];
  s0[i0] = a0; s0[i1] = a1;
  __syncthreads();

  // Hillis-Steele inclusive scan (ping-pong)
  float* src = s0;
  float* dst = s1;
  for (int off = 1; off < 512; off <<= 1) {
    float v0 = src[i0] + ((i0 >= off) ? src[i0 - off] : 0.0f);
    float v1 = src[i1] + ((i1 >= off) ? src[i1 - off] : 0.0f);
    dst[i0] = v0; dst[i1] = v1;
    __syncthreads();
    float* tmp = src; src = dst; dst = tmp;
  }

  // captured partials: exp(-(incl - a)) * absorb_tb
  float p = expf(-(src[i0] - a0)) * sab[i0] + expf(-(src[i1] - a1)) * sab[i1];
#pragma unroll
  for (int off = 32; off; off >>= 1) p += __shfl_down(p, off, 64);
  if ((t & 63) == 0) redc[t >> 6] = p;

  // z = [Xg, pooled/L]
  if (t < G_SZ) zz[t] = Xg[b * G_SZ + t];
  zz[G_SZ + i0] = pooled[b * H2_SZ + i0] * (1.0f / (float)L_SZ);
  zz[G_SZ + i1] = pooled[b * H2_SZ + i1] * (1.0f / (float)L_SZ);
  __syncthreads();

  // d1[j] = gelu(z . Wd1[:,j] + bd1[j]);  v = d1[j] * Wd2[j]
  float s = bd1[t];
  for (int cc = 0; cc < G_SZ + H2_SZ; ++cc) s = fmaf(zz[cc], Wd1[cc * DH_SZ + t], s);
  float v = gelu_exact(s) * Wd2[t];
#pragma unroll
  for (int off = 32; off; off >>= 1) v += __shfl_down(v, off, 64);
  if ((t & 63) == 0) redd[t >> 6] = v;
  __syncthreads();

  if (t == 0) {
    float captured = redc[0] + redc[1] + redc[2] + redc[3];
    float d = redd[0] + redd[1] + redd[2] + redd[3] + bd2[0];
    out[b] = captured + d;
  }
}

// ---------------------------------------------------------------------------
extern "C" void kernel_launch(void* const* d_in, const int* in_sizes, int n_in,
                              void* d_out, int out_size, void* d_ws, size_t ws_size,
                              hipStream_t stream) {
  const float* Xg  = (const float*)d_in[0];
  const float* Xl  = (const float*)d_in[1];
  const float* W1  = (const float*)d_in[2];
  const float* b1  = (const float*)d_in[3];
  const float* W2  = (const float*)d_in[4];
  const float* b2  = (const float*)d_in[5];
  const float* wa  = (const float*)d_in[6];
  const float* ba  = (const float*)d_in[7];
  const float* wt  = (const float*)d_in[8];
  const float* bt  = (const float*)d_in[9];
  const float* Wd1 = (const float*)d_in[10];
  const float* bd1 = (const float*)d_in[11];
  const float* Wd2 = (const float*)d_in[12];
  const float* bd2 = (const float*)d_in[13];

  char* ws = (char*)d_ws;
  __bf16* W1p    = (__bf16*)(ws + 0);            //  65536 B
  __bf16* W2p    = (__bf16*)(ws + 65536);        // 524288 B
  __bf16* W3p    = (__bf16*)(ws + 589824);       //  16384 B
  float* absorbW = (float*)(ws + 606208);        // 524288 B
  float* attenW  = (float*)(ws + 1130496);       // 524288 B
  float* pooled  = (float*)(ws + 1654784);       // 524288 B  (end 2179072)

  repack_kernel<<<148, 256, 0, stream>>>(W1, W2, wa, wt, W1p, W2p, W3p, pooled);
  fused_kernel<<<M_SZ / 64, 1024, 0, stream>>>(Xl, W1p, W2p, W3p, b1, b2,
                                               ba, bt, absorbW, attenW, pooled);
  finalize_kernel<<<B_SZ, 256, 0, stream>>>(Xg, absorbW, attenW, pooled,
                                            Wd1, bd1, Wd2, bd2, (float*)d_out);
}

// Round 12
// 140.136 us; speedup vs baseline: 1.0421x; 1.0421x over previous
//
#include <hip/hip_runtime.h>
#include <hip/hip_bf16.h>
#include <math.h>

// Shapes (fixed by the reference)
#define B_SZ   256
#define L_SZ   512
#define FD_SZ  64
#define H1_SZ  512
#define H2_SZ  512
#define G_SZ   32
#define DH_SZ  256
#define M_SZ   (B_SZ * L_SZ)   // 131072 rows

#define H1STRIDE 520           // padded row stride (elements): linear LDS
                               // addressing (immediate offsets), 4-way banks

typedef __bf16 bfx8 __attribute__((ext_vector_type(8)));
typedef __bf16 bfx4 __attribute__((ext_vector_type(4)));
typedef float  f32x4 __attribute__((ext_vector_type(4)));
typedef float  f32x16 __attribute__((ext_vector_type(16)));

__device__ __forceinline__ float gelu_exact(float x) {
  return 0.5f * x * (1.0f + erff(x * 0.70710678118654752440f));
}
// tanh-form gelu via sigmoid; log2(e) folded in so v_exp_f32 is used directly.
__device__ __forceinline__ float gelu_fast(float x) {
  float x2 = x * x;
  float w = x * fmaf(0.102943398f, x2, 2.30220931f);
  float e = __builtin_amdgcn_exp2f(-w);
  return x * __builtin_amdgcn_rcpf(1.0f + e);
}
__device__ __forceinline__ float softplus_f(float x) {
  return (x > 20.0f) ? x : log1pf(expf(x));
}
__device__ __forceinline__ __bf16 f2bf(float f) { return (__bf16)f; }

// DPP row_ror:n within each 16-lane row (pure VALU, no LDS pipe).
#define ROR_ADD(x, n)                                                          \
  {                                                                            \
    int _t = __builtin_amdgcn_mov_dpp(__builtin_bit_cast(int, (x)),            \
                                      0x120 + (n), 0xF, 0xF, true);            \
    (x) += __builtin_bit_cast(float, _t);                                      \
  }

#define MFMA16(a, b, c) __builtin_amdgcn_mfma_f32_16x16x32_bf16((a), (b), (c), 0, 0, 0)
#define MFMA32(a, b, c) __builtin_amdgcn_mfma_f32_32x32x16_bf16((a), (b), (c), 0, 0, 0)

// ---------------------------------------------------------------------------
// Repack W1 (64x512) fp32 -> bf16 16x16x32-B-fragment order:
//   block id = mb*2 + ks (mb: H1/16, ks: FD/32); lane l holds
//   W1[ks*32 + (l>>4)*8 + j][16*mb + (l&15)], j=0..7.
// Repack W2 (512x512) fp32 -> bf16 32x32x16-B-fragment order:
//   block id = nb*32 + ks (nb: H2/32, ks: H1/16); lane l holds
//   W2[16*ks + (l>>5)*8 + j][32*nb + (l&31)], j=0..7.
// Also zeroes `pooled` (512 KB).
// ---------------------------------------------------------------------------
__global__ void repack_kernel(const float* __restrict__ W1,
                              const float* __restrict__ W2,
                              __bf16* __restrict__ W1p,
                              __bf16* __restrict__ W2p,
                              float* __restrict__ pooled) {
  int t = blockIdx.x * 256 + threadIdx.x;
  // zero pooled: 131072 floats = 32768 float4
  if (t < 32768)
    *reinterpret_cast<float4*>(pooled + (size_t)t * 4) = (float4){0.f, 0.f, 0.f, 0.f};
  if (t < 4096) {  // W1: 64 blocks * 64 lanes
    int lane = t & 63, blk = t >> 6;
    int ks = blk & 1, mb = blk >> 1;
    int col = 16 * mb + (lane & 15);
    int kbase = ks * 32 + (lane >> 4) * 8;
    bfx8 o;
#pragma unroll
    for (int j = 0; j < 8; ++j) o[j] = f2bf(W1[(size_t)(kbase + j) * H1_SZ + col]);
    *reinterpret_cast<bfx8*>(W1p + (size_t)t * 8) = o;
  } else if (t < 4096 + 32768) {  // W2: 512 blocks * 64 lanes (32x32x16 frags)
    int t2 = t - 4096;
    int lane = t2 & 63, blk = t2 >> 6;
    int ks = blk & 31, nb = blk >> 5;
    int col = 32 * nb + (lane & 31);
    int kbase = 16 * ks + (lane >> 5) * 8;
    bfx8 o;
#pragma unroll
    for (int j = 0; j < 8; ++j) o[j] = f2bf(W2[(size_t)(kbase + j) * H2_SZ + col]);
    *reinterpret_cast<bfx8*>(W2p + (size_t)t2 * 8) = o;
  }
}

// ---------------------------------------------------------------------------
// Fused kernel: 64 rows per workgroup, 1024 threads (16 waves), 8 waves/SIMD.
// Wave w owns 32 h-columns.
//  GEMM1 (16x16x32, transposed): h1 cols 32w..32w+31, all 64 rows.
//  GEMM2 (32x32x16): h2 cols 32w..32w+31 (nb=w), rows 0..63, K=512.
//  Epilogue: butterfly-reduced absorb/atten + pooled.
// H1s uses PADDED stride 520 (no XOR): all LDS addresses are base+immediate.
// LDS: 65 KB H1s + 8 KB (Xs aliased with sl) = 73 KB -> 2 blocks/CU.
// ---------------------------------------------------------------------------
__global__ __launch_bounds__(1024, 8) void fused_kernel(
    const float* __restrict__ Xl,
    const __bf16* __restrict__ W1p, const __bf16* __restrict__ W2p,
    const float* __restrict__ b1, const float* __restrict__ b2,
    const float* __restrict__ wa, const float* __restrict__ ba,
    const float* __restrict__ wt, const float* __restrict__ bt,
    float* __restrict__ absorbW, float* __restrict__ attenW,
    float* __restrict__ pooled) {
  __shared__ __align__(16) char smem0[8192];  // Xs (GEMM1) then sl (epilogue)
  __shared__ __bf16 H1s[64 * H1STRIDE];       // 65 KB, padded, linear addr
  __bf16* Xs = reinterpret_cast<__bf16*>(smem0);  // 64x64, 16B-chunk XOR swz
  float*  sl = reinterpret_cast<float*>(smem0);   // 16 waves x 64 rows x 2

  const int tid = threadIdx.x;
  const int lane = tid & 63;
  const int w = tid >> 6;        // wave 0..15
  const int g = lane >> 4;       // k-group 0..3 (16x16x32 frags)
  const int c = lane & 15;       // row/col within 16x16 fragment
  const int c32 = lane & 31;     // col within 32x32 fragment
  const int kg = lane >> 5;      // k-group 0..1 (32x32x16 frags)
  const int R0 = blockIdx.x * 64;
  const int bidx = R0 >> 9;      // batch index (tiles aligned within batch)

  // ---- stage Xl tile (64x64 fp32 -> bf16 LDS, swizzled; convert ONCE) ----
  {
    int idx = tid;                // float4 unit 0..1023 (one per thread)
    int r = idx >> 4;
    int c4 = idx & 15;            // 16 float4 per row
    float4 v = *reinterpret_cast<const float4*>(Xl + (size_t)(R0 + r) * FD_SZ + c4 * 4);
    bfx4 bv;
    bv[0] = f2bf(v.x); bv[1] = f2bf(v.y); bv[2] = f2bf(v.z); bv[3] = f2bf(v.w);
    int chunk = c4 >> 1;          // 8-elem (16B) chunk 0..7
    int off = r * 64 + (((chunk ^ (r & 7)) << 3) + (c4 & 1) * 4);
    *reinterpret_cast<bfx4*>(&Xs[off]) = bv;
  }
  __syncthreads();

  // ---- GEMM1 (transposed): wave computes h1 cols 32w..32w+31 --------------
  f32x4 acc1[2][4];
#pragma unroll
  for (int mi = 0; mi < 2; ++mi)
#pragma unroll
    for (int ni = 0; ni < 4; ++ni) acc1[mi][ni] = (f32x4){0.f, 0.f, 0.f, 0.f};

#pragma unroll
  for (int ks = 0; ks < 2; ++ks) {
    bfx8 a1[2];
#pragma unroll
    for (int mi = 0; mi < 2; ++mi) {
      int mb = 2 * w + mi;
      a1[mi] = *reinterpret_cast<const bfx8*>(W1p + ((size_t)(mb * 2 + ks) * 64 + lane) * 8);
    }
    bfx8 bx[4];
#pragma unroll
    for (int ni = 0; ni < 4; ++ni) {
      int r = 16 * ni + c;
      int chunk = ks * 4 + g;
      bx[ni] = *reinterpret_cast<const bfx8*>(&Xs[r * 64 + ((chunk ^ (r & 7)) << 3)]);
    }
#pragma unroll
    for (int mi = 0; mi < 2; ++mi)
#pragma unroll
      for (int ni = 0; ni < 4; ++ni)
        acc1[mi][ni] = MFMA16(a1[mi], bx[ni], acc1[mi][ni]);
  }

  // epilogue GEMM1: bias + gelu -> bf16 -> H1s[row][k], k = 16*mb + 4*g + reg
  // padded layout: element offset = r*520 + k  (all mi/ni terms immediate)
#pragma unroll
  for (int mi = 0; mi < 2; ++mi) {
    int mb = 2 * w + mi;
    float4 bias4 = *reinterpret_cast<const float4*>(b1 + 16 * mb + 4 * g);
#pragma unroll
    for (int ni = 0; ni < 4; ++ni) {
      int r = 16 * ni + c;                 // x-row (0..63)
      bfx4 pv;
      pv[0] = f2bf(gelu_fast(acc1[mi][ni][0] + bias4.x));
      pv[1] = f2bf(gelu_fast(acc1[mi][ni][1] + bias4.y));
      pv[2] = f2bf(gelu_fast(acc1[mi][ni][2] + bias4.z));
      pv[3] = f2bf(gelu_fast(acc1[mi][ni][3] + bias4.w));
      int off = r * H1STRIDE + 16 * mb + 4 * g;
      *reinterpret_cast<bfx4*>(&H1s[off]) = pv;
    }
  }
  __syncthreads();

  // ---- GEMM2 (32x32x16): wave w owns cols 32w..32w+31 (nb=w), rows 0..63 --
  f32x16 acc2[2];   // [mblk] -> 32 AGPR
#pragma unroll
  for (int m = 0; m < 2; ++m)
#pragma unroll
    for (int q = 0; q < 16; ++q) acc2[m][q] = 0.0f;

  const __bf16* wpb = W2p + ((size_t)w * 32 * 64 + lane) * 8;
  // per-lane base: row = c32 (m term = immediate), k-chunk base = 8*kg elems
  const __bf16* h1base = &H1s[c32 * H1STRIDE + 8 * kg];
  for (int ks = 0; ks < 32; ++ks) {
    bfx8 a2[2];
#pragma unroll
    for (int m = 0; m < 2; ++m)   // offset = m*32*520 + ks*16 elems (imm)
      a2[m] = *reinterpret_cast<const bfx8*>(h1base + m * 32 * H1STRIDE + ks * 16);
    bfx8 bw = *reinterpret_cast<const bfx8*>(wpb + (size_t)ks * 512);
    __builtin_amdgcn_s_setprio(1);
    acc2[0] = MFMA32(a2[0], bw, acc2[0]);
    acc2[1] = MFMA32(a2[1], bw, acc2[1]);
    __builtin_amdgcn_s_setprio(0);
  }

  // ---- epilogue GEMM2: bias+gelu, butterfly-reduce absorb/atten + pooled ---
  // C layout (32x32): col = lane&31, row = (reg&3) + 8*(reg>>2) + 4*(lane>>5)
  const int col = 32 * w + c32;
  const float b2v = b2[col];
  const float wav = wa[col];
  const float wtv = wt[col];
  float pool0 = 0.0f;
  const int rbase = 4 * kg;
  const bool hi16 = (lane & 16) != 0;

#pragma unroll
  for (int m = 0; m < 2; ++m) {
#pragma unroll
    for (int q = 0; q < 8; ++q) {
      int rA = 2 * q, rB = 2 * q + 1;
      float vA = gelu_fast(acc2[m][rA] + b2v);
      float vB = gelu_fast(acc2[m][rB] + b2v);
      pool0 += vA + vB;
      float saA = vA * wav, saB = vB * wav;
      float stA = vA * wtv, stB = vB * wtv;
      // 2-for-1 butterfly at the xor16 level, then shared 16-lane DPP tree.
      float zs = hi16 ? saB : saA;
      float ys = hi16 ? saA : saB;
      float zt = hi16 ? stB : stA;
      float yt = hi16 ? stA : stB;
      ys = __shfl_xor(ys, 16, 64);
      yt = __shfl_xor(yt, 16, 64);
      float ss = zs + ys;         // lanes c32<16: rowA partial; >=16: rowB
      float tt = zt + yt;
      ROR_ADD(ss, 8); ROR_ADD(ss, 4); ROR_ADD(ss, 2); ROR_ADD(ss, 1);
      ROR_ADD(tt, 8); ROR_ADD(tt, 4); ROR_ADD(tt, 2); ROR_ADD(tt, 1);
      if (c32 == 0) {
        int row = 32 * m + (rA & 3) + 8 * (rA >> 2) + rbase;
        *reinterpret_cast<float2*>(&sl[w * 128 + row * 2]) = make_float2(ss, tt);
      } else if (c32 == 16) {
        int row = 32 * m + (rB & 3) + 8 * (rB >> 2) + rbase;
        *reinterpret_cast<float2*>(&sl[w * 128 + row * 2]) = make_float2(ss, tt);
      }
    }
  }
  // pooled: col sums need the two lane-halves (row sets) combined
  pool0 += __shfl_xor(pool0, 32, 64);
  if (lane < 32)
    atomicAdd(&pooled[bidx * H2_SZ + 32 * w + c32], pool0);
  __syncthreads();

  if (tid < 64) {
    float sa = 0.0f, st = 0.0f;
#pragma unroll
    for (int w16 = 0; w16 < 16; ++w16) {
      float2 v2 = *reinterpret_cast<float2*>(&sl[w16 * 128 + tid * 2]);
      sa += v2.x; st += v2.y;
    }
    absorbW[R0 + tid] = softplus_f(sa + ba[0]);
    attenW[R0 + tid]  = softplus_f(st + bt[0]);
  }
}

// ---------------------------------------------------------------------------
// Finalize: per-b reversed exclusive-cumsum scan + captured, pooled head, out
// ---------------------------------------------------------------------------
__global__ __launch_bounds__(256) void finalize_kernel(
    const float* __restrict__ Xg,
    const float* __restrict__ absorbW, const float* __restrict__ attenW,
    const float* __restrict__ pooled,
    const float* __restrict__ Wd1, const float* __restrict__ bd1,
    const float* __restrict__ Wd2, const float* __restrict__ bd2,
    float* __restrict__ out) {
  __shared__ float s0[512];
  __shared__ float s1[512];
  __shared__ float sab[512];
  __shared__ float zz[544];
  __shared__ float redc[4];
  __shared__ float redd[4];

  const int b = blockIdx.x;
  const int t = threadIdx.x;
  const int i0 = t, i1 = t + 256;

  // load time-reversed absorb/atten
  float a0 = attenW[b * L_SZ + (L_SZ - 1 - i0)];
  float a1 = attenW[b * L_SZ + (L_SZ - 1 - i1)];
  sab[i0] = absorbW[b * L_SZ + (L_SZ - 1 - i0)];
  sab[i1] = absorbW[b * L_SZ + (L_SZ - 1 - i1)];
  s0[i0] = a0; s0[i1] = a1;
  __syncthreads();

  // Hillis-Steele inclusive scan (ping-pong)
  float* src = s0;
  float* dst = s1;
  for (int off = 1; off < 512; off <<= 1) {
    float v0 = src[i0] + ((i0 >= off) ? src[i0 - off] : 0.0f);
    float v1 = src[i1] + ((i1 >= off) ? src[i1 - off] : 0.0f);
    dst[i0] = v0; dst[i1] = v1;
    __syncthreads();
    float* tmp = src; src = dst; dst = tmp;
  }

  // captured partials: exp(-(incl - a)) * absorb_tb
  float p = expf(-(src[i0] - a0)) * sab[i0] + expf(-(src[i1] - a1)) * sab[i1];
#pragma unroll
  for (int off = 32; off; off >>= 1) p += __shfl_down(p, off, 64);
  if ((t & 63) == 0) redc[t >> 6] = p;

  // z = [Xg, pooled/L]
  if (t < G_SZ) zz[t] = Xg[b * G_SZ + t];
  zz[G_SZ + i0] = pooled[b * H2_SZ + i0] * (1.0f / (float)L_SZ);
  zz[G_SZ + i1] = pooled[b * H2_SZ + i1] * (1.0f / (float)L_SZ);
  __syncthreads();

  // d1[j] = gelu(z . Wd1[:,j] + bd1[j]);  v = d1[j] * Wd2[j]
  float s = bd1[t];
  for (int cc = 0; cc < G_SZ + H2_SZ; ++cc) s = fmaf(zz[cc], Wd1[cc * DH_SZ + t], s);
  float v = gelu_exact(s) * Wd2[t];
#pragma unroll
  for (int off = 32; off; off >>= 1) v += __shfl_down(v, off, 64);
  if ((t & 63) == 0) redd[t >> 6] = v;
  __syncthreads();

  if (t == 0) {
    float captured = redc[0] + redc[1] + redc[2] + redc[3];
    float d = redd[0] + redd[1] + redd[2] + redd[3] + bd2[0];
    out[b] = captured + d;
  }
}

// ---------------------------------------------------------------------------
extern "C" void kernel_launch(void* const* d_in, const int* in_sizes, int n_in,
                              void* d_out, int out_size, void* d_ws, size_t ws_size,
                              hipStream_t stream) {
  const float* Xg  = (const float*)d_in[0];
  const float* Xl  = (const float*)d_in[1];
  const float* W1  = (const float*)d_in[2];
  const float* b1  = (const float*)d_in[3];
  const float* W2  = (const float*)d_in[4];
  const float* b2  = (const float*)d_in[5];
  const float* wa  = (const float*)d_in[6];
  const float* ba  = (const float*)d_in[7];
  const float* wt  = (const float*)d_in[8];
  const float* bt  = (const float*)d_in[9];
  const float* Wd1 = (const float*)d_in[10];
  const float* bd1 = (const float*)d_in[11];
  const float* Wd2 = (const float*)d_in[12];
  const float* bd2 = (const float*)d_in[13];

  char* ws = (char*)d_ws;
  __bf16* W1p    = (__bf16*)(ws + 0);            //  65536 B
  __bf16* W2p    = (__bf16*)(ws + 65536);        // 524288 B
  float* absorbW = (float*)(ws + 589824);        // 524288 B
  float* attenW  = (float*)(ws + 1114112);       // 524288 B
  float* pooled  = (float*)(ws + 1638400);       // 524288 B  (end 2162688)

  repack_kernel<<<144, 256, 0, stream>>>(W1, W2, W1p, W2p, pooled);
  fused_kernel<<<M_SZ / 64, 1024, 0, stream>>>(Xl, W1p, W2p, b1, b2, wa, ba,
                                               wt, bt, absorbW, attenW, pooled);
  finalize_kernel<<<B_SZ, 256, 0, stream>>>(Xg, absorbW, attenW, pooled,
                                            Wd1, bd1, Wd2, bd2, (float*)d_out);
}